// Round 6
// baseline (1075.268 us; speedup 1.0000x reference)
//
#include <hip/hip_runtime.h>
#include <cstddef>
#include <cstdint>

typedef short bf16x8 __attribute__((ext_vector_type(8)));
typedef float f32x4 __attribute__((ext_vector_type(4)));

#define MFMA16(a, b, c) __builtin_amdgcn_mfma_f32_16x16x32_bf16((a), (b), (c), 0, 0, 0)

__device__ __forceinline__ unsigned short f2bf(float f) {
  unsigned u = __float_as_uint(f);
  u = (u + 0x7FFFu + ((u >> 16) & 1u)) >> 16;
  return (unsigned short)u;
}
__device__ __forceinline__ float bf2f(unsigned short h) {
  return __uint_as_float(((unsigned)h) << 16);
}

// ---------------------------------------------------------------------------
// Weight prep (round-2 proven version): fold BN into Wqk/Wv (bf16) + f32 bias;
// cast Wproj; transpose dw weights to [k][c].
// ---------------------------------------------------------------------------
__global__ void wprep(const float* __restrict__ bn_g, const float* __restrict__ bn_b,
                      const float* __restrict__ bn_m, const float* __restrict__ bn_v,
                      const float* __restrict__ w_qk, const float* __restrict__ w_v,
                      const float* __restrict__ w_proj,
                      const float* __restrict__ w3, const float* __restrict__ w5,
                      const float* __restrict__ w7,
                      unsigned short* __restrict__ Wqk, unsigned short* __restrict__ Wv,
                      unsigned short* __restrict__ Wp,
                      float* __restrict__ bqk, float* __restrict__ bv,
                      float* __restrict__ w3T, float* __restrict__ w5T,
                      float* __restrict__ w7T) {
  int blk = blockIdx.x, t = threadIdx.x;
  if (blk == 4) {
    for (int idx = t; idx < 21248; idx += 256) {
      if (idx < 2304) {
        int k2 = idx >> 8, c = idx & 255;
        w3T[idx] = w3[c * 9 + k2];
      } else if (idx < 8704) {
        int i = idx - 2304;
        int k2 = i >> 8, c = i & 255;
        w5T[i] = w5[c * 25 + k2];
      } else {
        int i = idx - 8704;
        int k2 = i >> 8, c = i & 255;
        w7T[i] = w7[c * 49 + k2];
      }
    }
    return;
  }
  int o = blk * 256 + t;  // 0..1023
  if (o < 512) {
    float scale = (o < 256) ? 0.125f : 1.0f;  // q rows get 1/sqrt(64)
    float bias = 0.f;
    for (int c = 0; c < 256; ++c) {
      float g = bn_g[c] / sqrtf(bn_v[c] + 1e-5f);
      float be = bn_b[c] - bn_m[c] * g;
      float wv = w_qk[o * 256 + c];
      bias += wv * be;
      Wqk[o * 256 + c] = f2bf(wv * g * scale);
    }
    bqk[o] = bias * scale;
  } else if (o < 768) {
    int oo = o - 512;
    float bias = 0.f;
    for (int c = 0; c < 256; ++c) {
      float g = bn_g[c] / sqrtf(bn_v[c] + 1e-5f);
      float be = bn_b[c] - bn_m[c] * g;
      float wv = w_v[oo * 256 + c];
      bias += wv * be;
      Wv[oo * 256 + c] = f2bf(wv * g);
    }
    bv[oo] = bias;
  } else {
    int oo = o - 768;
    for (int c = 0; c < 256; ++c) Wp[oo * 256 + c] = f2bf(w_proj[oo * 256 + c]);
  }
}

// ---------------------------------------------------------------------------
// Transpose+cast: x f32 [32][256][3136] -> xT bf16 [pix=32*3136][256]
// ---------------------------------------------------------------------------
__global__ __launch_bounds__(256) void xpose(const float* __restrict__ x,
                                             unsigned short* __restrict__ xT) {
  __shared__ float tile[64 * 68];
  int blk = blockIdx.x;
  int bb = blk / 196;
  int rem = blk - bb * 196;
  int cblk = rem / 49;
  int pblk = rem - cblk * 49;
  int t = threadIdx.x;
  {
    int r = t >> 2, seg = t & 3;
    const float* src = x + (size_t)bb * 802816 + (size_t)(cblk * 64 + r) * 3136 +
                       pblk * 64 + seg * 16;
    float4 v0 = ((const float4*)src)[0];
    float4 v1 = ((const float4*)src)[1];
    float4 v2 = ((const float4*)src)[2];
    float4 v3 = ((const float4*)src)[3];
    float* td = tile + r * 68 + seg * 16;
    td[0] = v0.x; td[1] = v0.y; td[2] = v0.z; td[3] = v0.w;
    td[4] = v1.x; td[5] = v1.y; td[6] = v1.z; td[7] = v1.w;
    td[8] = v2.x; td[9] = v2.y; td[10] = v2.z; td[11] = v2.w;
    td[12] = v3.x; td[13] = v3.y; td[14] = v3.z; td[15] = v3.w;
  }
  __syncthreads();
  {
    int p = t >> 2, cs = t & 3;
    alignas(16) unsigned short tmp[16];
#pragma unroll
    for (int u = 0; u < 16; ++u) tmp[u] = f2bf(tile[(cs * 16 + u) * 68 + p]);
    unsigned short* dst = xT + (size_t)(bb * 3136 + pblk * 64 + p) * 256 +
                          cblk * 64 + cs * 16;
    ((uint4*)dst)[0] = *(const uint4*)(tmp);
    ((uint4*)dst)[1] = *(const uint4*)(tmp + 8);
  }
}

// ---------------------------------------------------------------------------
// Fused per-window kernel — round-2 numerics, one head per iteration.
// LDS (74,112 B -> 2 blocks/CU), ALL regions dedicated (zero aliasing):
//   xw    [49][264] bf16 :      0 .. 25872
//   v_lds [65][56]  bf16 :  25872 .. 33152  (per-head; row 64 els0..7 = guard 0)
//   q_lds [64][72]  bf16 :  33152 .. 42368
//   k_lds [64][72]  bf16 :  42368 .. 51584
//   Sb    [64][72]  bf16 :  51584 .. 60800
//   spa   [64][52]  f32  :  60800 .. 74112  (raw PV, no attn_w folded)
// ---------------------------------------------------------------------------
__global__ __launch_bounds__(512, 4) void k2_win(
    const unsigned short* __restrict__ xT, const unsigned short* __restrict__ Wqk,
    const unsigned short* __restrict__ Wv, const float* __restrict__ bqk,
    const float* __restrict__ bv, const float* __restrict__ w3T,
    const float* __restrict__ w5T, const float* __restrict__ w7T,
    const float* __restrict__ aw, const float* __restrict__ c3w,
    const float* __restrict__ c5w, const float* __restrict__ c7w,
    unsigned short* __restrict__ xcT) {
  extern __shared__ char smem[];
  unsigned short* xw = (unsigned short*)smem;
  unsigned short* v_lds = (unsigned short*)(smem + 25872);
  unsigned short* q_lds = (unsigned short*)(smem + 33152);
  unsigned short* k_lds = (unsigned short*)(smem + 42368);
  unsigned short* Sb = (unsigned short*)(smem + 51584);
  float* spa = (float*)(smem + 60800);

  const int tid = threadIdx.x;
  const int l = tid & 63, w = tid >> 6, l15 = l & 15, lg = l >> 4;
  const int blk = blockIdx.x;
  const int bb = blk >> 6, i1 = (blk >> 3) & 7, i2 = blk & 7;

  // ---- A: gather window rows of xT into LDS [p][c]; zero v guard row
  for (int idx = tid; idx < 1568; idx += 512) {
    int r = idx >> 5, seg = idx & 31;
    int h1 = (r * 9363) >> 16, w1 = r - h1 * 7;
    int pix = bb * 3136 + (h1 * 8 + i1) * 56 + w1 * 8 + i2;
    *(uint4*)(xw + r * 264 + seg * 8) =
        *(const uint4*)(xT + (size_t)pix * 256 + seg * 8);
  }
  if (tid < 8) v_lds[64 * 56 + tid] = 0;  // PV row-overrun guard
  __syncthreads();

  // ---- per-head pipeline
  for (int h = 0; h < 4; ++h) {
    // C1: waves 0-3 -> q-tile w AND v-tile w; waves 4-7 -> k-tile (w-4).
    {
      const bool isq = (w < 4);
      const int wt = isq ? w : (w - 4);
      const int obase = isq ? (h * 64 + wt * 16) : (256 + h * 64 + wt * 16);
      f32x4 aq[4], av[4];
#pragma unroll
      for (int nt = 0; nt < 4; ++nt) {
        aq[nt] = (f32x4){0.f, 0.f, 0.f, 0.f};
        av[nt] = (f32x4){0.f, 0.f, 0.f, 0.f};
      }
#pragma unroll 2
      for (int ks = 0; ks < 8; ++ks) {
        bf16x8 b[4];
#pragma unroll
        for (int nt = 0; nt < 4; ++nt) {
          int j = nt * 16 + l15;
          if (j > 48) j = 48;
          b[nt] = *(const bf16x8*)(xw + j * 264 + ks * 32 + lg * 8);
        }
        bf16x8 a0 = *(const bf16x8*)(Wqk + (obase + l15) * 256 + ks * 32 + lg * 8);
#pragma unroll
        for (int nt = 0; nt < 4; ++nt) aq[nt] = MFMA16(a0, b[nt], aq[nt]);
        if (isq) {
          bf16x8 a1 =
              *(const bf16x8*)(Wv + (h * 64 + wt * 16 + l15) * 256 + ks * 32 + lg * 8);
#pragma unroll
          for (int nt = 0; nt < 4; ++nt) av[nt] = MFMA16(a1, b[nt], av[nt]);
        }
      }
      unsigned short* dst = isq ? q_lds : k_lds;
#pragma unroll
      for (int ri = 0; ri < 4; ++ri) {
        float bias = bqk[obase + lg * 4 + ri];
        int d = wt * 16 + lg * 4 + ri;
#pragma unroll
        for (int nt = 0; nt < 4; ++nt) {
          int p = nt * 16 + l15;
          dst[p * 72 + d] = f2bf(aq[nt][ri] + bias);
        }
      }
      if (isq) {
#pragma unroll
        for (int ri = 0; ri < 4; ++ri) {
          int cl = wt * 16 + lg * 4 + ri;
          float bvv = bv[h * 64 + cl];
#pragma unroll
          for (int nt = 0; nt < 4; ++nt) {
            int p = nt * 16 + l15;
            if (p < 56) v_lds[cl * 56 + p] = f2bf(av[nt][ri] + bvv);
          }
        }
      }
    }
    __syncthreads();

    // C2 (waves 0-3): S = q k^T, softmax in regs, write Sb (dedicated buffer)
    if (w < 4) {
      f32x4 s[4];
#pragma unroll
      for (int nt = 0; nt < 4; ++nt) s[nt] = (f32x4){0.f, 0.f, 0.f, 0.f};
#pragma unroll
      for (int ks = 0; ks < 2; ++ks) {
        bf16x8 a = *(const bf16x8*)(q_lds + (w * 16 + l15) * 72 + ks * 32 + lg * 8);
        bf16x8 b[4];
#pragma unroll
        for (int nt = 0; nt < 4; ++nt)
          b[nt] = *(const bf16x8*)(k_lds + (nt * 16 + l15) * 72 + ks * 32 + lg * 8);
#pragma unroll
        for (int nt = 0; nt < 4; ++nt) s[nt] = MFMA16(a, b[nt], s[nt]);
      }
#pragma unroll
      for (int ri = 0; ri < 4; ++ri) {
        float s0 = s[0][ri], s1 = s[1][ri], s2 = s[2][ri], s3 = s[3][ri];
        if (l15 != 0) s3 = -1e30f;  // mask j = 49..63
        float m = fmaxf(fmaxf(s0, s1), fmaxf(s2, s3));
        m = fmaxf(m, __shfl_xor(m, 1));
        m = fmaxf(m, __shfl_xor(m, 2));
        m = fmaxf(m, __shfl_xor(m, 4));
        m = fmaxf(m, __shfl_xor(m, 8));
        float e0 = __expf(s0 - m), e1 = __expf(s1 - m);
        float e2 = __expf(s2 - m), e3 = __expf(s3 - m);
        float sum = e0 + e1 + e2 + e3;
        sum += __shfl_xor(sum, 1);
        sum += __shfl_xor(sum, 2);
        sum += __shfl_xor(sum, 4);
        sum += __shfl_xor(sum, 8);
        float inv = 1.f / sum;
        int row = w * 16 + lg * 4 + ri;
        unsigned short* sb = Sb + row * 72 + l15;
        sb[0] = f2bf(e0 * inv);
        sb[16] = f2bf(e1 * inv);
        sb[32] = f2bf(e2 * inv);
        sb[48] = f2bf(e3 * inv);
      }
    }
    __syncthreads();

    // C3: PV (M=64 p, N=64 c', K=64) -> spa f32 (raw, no attn_w)
    {
      int pr = w & 3, nc = (w >> 2) * 2;
      f32x4 acc[2];
      acc[0] = (f32x4){0.f, 0.f, 0.f, 0.f};
      acc[1] = (f32x4){0.f, 0.f, 0.f, 0.f};
#pragma unroll
      for (int ks = 0; ks < 2; ++ks) {
        bf16x8 a = *(const bf16x8*)(Sb + (pr * 16 + l15) * 72 + ks * 32 + lg * 8);
#pragma unroll
        for (int t = 0; t < 2; ++t) {
          bf16x8 b = *(const bf16x8*)(v_lds + ((nc + t) * 16 + l15) * 56 +
                                      ks * 32 + lg * 8);
          acc[t] = MFMA16(a, b, acc[t]);
        }
      }
#pragma unroll
      for (int t = 0; t < 2; ++t) {
        int cl = (nc + t) * 16 + l15;
#pragma unroll
        for (int ri = 0; ri < 4; ++ri) {
          int p = pr * 16 + lg * 4 + ri;
          if (p < 49) spa[cl * 52 + p] = acc[t][ri];
        }
      }
    }
    __syncthreads();

    // C4 (round-2 body): separate 3/5/7 convs + weighted fusion + residual,
    // wave w = window row hr (waves 0-6), lane = channel; coalesced global write.
    if (w < 7) {
      int cl = l;                 // channel within head
      int c = h * 64 + cl;        // global channel
      int hr = w;                 // window row (wave-uniform)
      const float* spaC = spa + cl * 52;
      float awc = aw[c], c3c = c3w[c], c5c = c5w[c], c7c = c7w[c];
      float W3[9], W5[25], W7[49];
#pragma unroll
      for (int k2 = 0; k2 < 9; ++k2) W3[k2] = w3T[k2 * 256 + c];
#pragma unroll
      for (int k2 = 0; k2 < 25; ++k2) W5[k2] = w5T[k2 * 256 + c];
#pragma unroll
      for (int k2 = 0; k2 < 49; ++k2) W7[k2] = w7T[k2 * 256 + c];
      float vr[7][7];
#pragma unroll
      for (int dy = -3; dy <= 3; ++dy) {
        int ry = hr + dy;
        if ((unsigned)ry < 7u) {
#pragma unroll
          for (int cc = 0; cc < 7; ++cc)
            vr[dy + 3][cc] = bf2f(v_lds[cl * 56 + ry * 7 + cc]);
        }
      }
      float sp[7];
#pragma unroll
      for (int ww = 0; ww < 7; ++ww) sp[ww] = spaC[hr * 7 + ww];
#pragma unroll
      for (int ww = 0; ww < 7; ++ww) {
        float s3a = 0.f, s5a = 0.f, s7a = 0.f;
#pragma unroll
        for (int dy = -3; dy <= 3; ++dy) {
          if ((unsigned)(hr + dy) < 7u) {
#pragma unroll
            for (int dx = -3; dx <= 3; ++dx) {
              int cc = ww + dx;
              if (cc >= 0 && cc < 7) {
                float vv = vr[dy + 3][cc];
                s7a = fmaf(W7[(dy + 3) * 7 + dx + 3], vv, s7a);
                if (dy >= -2 && dy <= 2 && dx >= -2 && dx <= 2)
                  s5a = fmaf(W5[(dy + 2) * 5 + dx + 2], vv, s5a);
                if (dy >= -1 && dy <= 1 && dx >= -1 && dx <= 1)
                  s3a = fmaf(W3[(dy + 1) * 3 + dx + 1], vv, s3a);
              }
            }
          }
        }
        float val = fmaf(sp[ww], awc,
                    fmaf(s3a, c3c,
                    fmaf(s5a, c5c,
                    fmaf(s7a, c7c, vr[3][ww]))));
        int pixp = bb * 3136 + (hr * 8 + i1) * 56 + ww * 8 + i2;
        xcT[(size_t)pixp * 256 + c] = f2bf(val);
      }
    }
    __syncthreads();
  }
}

// ---------------------------------------------------------------------------
// Proj GEMM (M=256, N=pix, K=256) + shortcut residual, f32 out
// ---------------------------------------------------------------------------
__global__ __launch_bounds__(256) void k3_proj(const unsigned short* __restrict__ Wp,
                                               const unsigned short* __restrict__ xcT,
                                               const float* __restrict__ x,
                                               float* __restrict__ out) {
  const int tid = threadIdx.x, l = tid & 63, w = tid >> 6;
  const int l15 = l & 15, lg = l >> 4;
  const int blk = blockIdx.x;
  f32x4 acc[4][4];
#pragma unroll
  for (int mf = 0; mf < 4; ++mf)
#pragma unroll
    for (int nf = 0; nf < 4; ++nf) acc[mf][nf] = (f32x4){0.f, 0.f, 0.f, 0.f};
#pragma unroll 2
  for (int ks = 0; ks < 8; ++ks) {
    bf16x8 a[4], b[4];
#pragma unroll
    for (int mf = 0; mf < 4; ++mf)
      a[mf] = *(const bf16x8*)(Wp + (w * 64 + mf * 16 + l15) * 256 + ks * 32 + lg * 8);
#pragma unroll
    for (int nf = 0; nf < 4; ++nf)
      b[nf] = *(const bf16x8*)(xcT + (size_t)(blk * 64 + nf * 16 + l15) * 256 +
                               ks * 32 + lg * 8);
#pragma unroll
    for (int mf = 0; mf < 4; ++mf)
#pragma unroll
      for (int nf = 0; nf < 4; ++nf) acc[mf][nf] = MFMA16(a[mf], b[nf], acc[mf][nf]);
  }
  int bb = (blk * 64) / 3136;
  int loc0 = blk * 64 - bb * 3136;
#pragma unroll
  for (int mf = 0; mf < 4; ++mf)
#pragma unroll
    for (int nf = 0; nf < 4; ++nf)
#pragma unroll
      for (int ri = 0; ri < 4; ++ri) {
        int o = w * 64 + mf * 16 + lg * 4 + ri;
        int ploc = loc0 + nf * 16 + l15;
        size_t addr = (size_t)bb * 802816 + (size_t)o * 3136 + ploc;
        out[addr] = x[addr] + acc[mf][nf][ri];
      }
}

// ---------------------------------------------------------------------------
extern "C" void kernel_launch(void* const* d_in, const int* in_sizes, int n_in,
                              void* d_out, int out_size, void* d_ws, size_t ws_size,
                              hipStream_t stream) {
  const float* x = (const float*)d_in[0];
  const float* bn_g = (const float*)d_in[1];
  const float* bn_b = (const float*)d_in[2];
  const float* bn_m = (const float*)d_in[3];
  const float* bn_v = (const float*)d_in[4];
  const float* w_qk = (const float*)d_in[5];
  const float* w_v = (const float*)d_in[6];
  const float* w3 = (const float*)d_in[7];
  const float* w5 = (const float*)d_in[8];
  const float* w7 = (const float*)d_in[9];
  const float* aw = (const float*)d_in[10];
  const float* c3w = (const float*)d_in[11];
  const float* c5w = (const float*)d_in[12];
  const float* c7w = (const float*)d_in[13];
  const float* w_pr = (const float*)d_in[14];
  float* out = (float*)d_out;
  char* ws = (char*)d_ws;

  unsigned short* Wqk = (unsigned short*)ws;               // 512x256 bf16
  unsigned short* Wv = (unsigned short*)(ws + 262144);     // 256x256 bf16
  unsigned short* Wp = (unsigned short*)(ws + 393216);     // 256x256 bf16
  float* bqk = (float*)(ws + 524288);                      // 512 f32
  float* bv = (float*)(ws + 526336);                       // 256 f32
  float* w3T = (float*)(ws + 527360);                      // 9x256
  float* w5T = (float*)(ws + 536576);                      // 25x256
  float* w7T = (float*)(ws + 562176);                      // 49x256
  unsigned short* xT = (unsigned short*)(ws + 1048576);    // 100352x256 bf16
  unsigned short* xcT = (unsigned short*)(ws + 52428800);  // 100352x256 bf16

  wprep<<<5, 256, 0, stream>>>(bn_g, bn_b, bn_m, bn_v, w_qk, w_v, w_pr, w3, w5, w7,
                               Wqk, Wv, Wp, bqk, bv, w3T, w5T, w7T);
  xpose<<<6272, 256, 0, stream>>>(x, xT);
  hipFuncSetAttribute(reinterpret_cast<const void*>(k2_win),
                      hipFuncAttributeMaxDynamicSharedMemorySize, 74112);
  k2_win<<<2048, 512, 74112, stream>>>(xT, Wqk, Wv, bqk, bv, w3T, w5T, w7T, aw, c3w,
                                       c5w, c7w, xcT);
  k3_proj<<<1568, 256, 0, stream>>>(Wp, xcT, x, out);
}

// Round 7
// 352.252 us; speedup vs baseline: 3.0526x; 3.0526x over previous
//
#include <hip/hip_runtime.h>
#include <cstddef>
#include <cstdint>

typedef short bf16x8 __attribute__((ext_vector_type(8)));
typedef float f32x4 __attribute__((ext_vector_type(4)));

#define MFMA16(a, b, c) __builtin_amdgcn_mfma_f32_16x16x32_bf16((a), (b), (c), 0, 0, 0)

__device__ __forceinline__ unsigned short f2bf(float f) {
  unsigned u = __float_as_uint(f);
  u = (u + 0x7FFFu + ((u >> 16) & 1u)) >> 16;
  return (unsigned short)u;
}
__device__ __forceinline__ float bf2f(unsigned short h) {
  return __uint_as_float(((unsigned)h) << 16);
}

// ---------------------------------------------------------------------------
// Weight prep (round-2 proven version): fold BN into Wqk/Wv (bf16) + f32 bias;
// cast Wproj; transpose dw weights to [k][c].
// ---------------------------------------------------------------------------
__global__ void wprep(const float* __restrict__ bn_g, const float* __restrict__ bn_b,
                      const float* __restrict__ bn_m, const float* __restrict__ bn_v,
                      const float* __restrict__ w_qk, const float* __restrict__ w_v,
                      const float* __restrict__ w_proj,
                      const float* __restrict__ w3, const float* __restrict__ w5,
                      const float* __restrict__ w7,
                      unsigned short* __restrict__ Wqk, unsigned short* __restrict__ Wv,
                      unsigned short* __restrict__ Wp,
                      float* __restrict__ bqk, float* __restrict__ bv,
                      float* __restrict__ w3T, float* __restrict__ w5T,
                      float* __restrict__ w7T) {
  int blk = blockIdx.x, t = threadIdx.x;
  if (blk == 4) {
    for (int idx = t; idx < 21248; idx += 256) {
      if (idx < 2304) {
        int k2 = idx >> 8, c = idx & 255;
        w3T[idx] = w3[c * 9 + k2];
      } else if (idx < 8704) {
        int i = idx - 2304;
        int k2 = i >> 8, c = i & 255;
        w5T[i] = w5[c * 25 + k2];
      } else {
        int i = idx - 8704;
        int k2 = i >> 8, c = i & 255;
        w7T[i] = w7[c * 49 + k2];
      }
    }
    return;
  }
  int o = blk * 256 + t;  // 0..1023
  if (o < 512) {
    float scale = (o < 256) ? 0.125f : 1.0f;  // q rows get 1/sqrt(64)
    float bias = 0.f;
    for (int c = 0; c < 256; ++c) {
      float g = bn_g[c] / sqrtf(bn_v[c] + 1e-5f);
      float be = bn_b[c] - bn_m[c] * g;
      float wv = w_qk[o * 256 + c];
      bias += wv * be;
      Wqk[o * 256 + c] = f2bf(wv * g * scale);
    }
    bqk[o] = bias * scale;
  } else if (o < 768) {
    int oo = o - 512;
    float bias = 0.f;
    for (int c = 0; c < 256; ++c) {
      float g = bn_g[c] / sqrtf(bn_v[c] + 1e-5f);
      float be = bn_b[c] - bn_m[c] * g;
      float wv = w_v[oo * 256 + c];
      bias += wv * be;
      Wv[oo * 256 + c] = f2bf(wv * g);
    }
    bv[oo] = bias;
  } else {
    int oo = o - 768;
    for (int c = 0; c < 256; ++c) Wp[oo * 256 + c] = f2bf(w_proj[oo * 256 + c]);
  }
}

// ---------------------------------------------------------------------------
// Transpose+cast: x f32 [32][256][3136] -> xT bf16 [pix=32*3136][256]
// ---------------------------------------------------------------------------
__global__ __launch_bounds__(256) void xpose(const float* __restrict__ x,
                                             unsigned short* __restrict__ xT) {
  __shared__ float tile[64 * 68];
  int blk = blockIdx.x;
  int bb = blk / 196;
  int rem = blk - bb * 196;
  int cblk = rem / 49;
  int pblk = rem - cblk * 49;
  int t = threadIdx.x;
  {
    int r = t >> 2, seg = t & 3;
    const float* src = x + (size_t)bb * 802816 + (size_t)(cblk * 64 + r) * 3136 +
                       pblk * 64 + seg * 16;
    float4 v0 = ((const float4*)src)[0];
    float4 v1 = ((const float4*)src)[1];
    float4 v2 = ((const float4*)src)[2];
    float4 v3 = ((const float4*)src)[3];
    float* td = tile + r * 68 + seg * 16;
    td[0] = v0.x; td[1] = v0.y; td[2] = v0.z; td[3] = v0.w;
    td[4] = v1.x; td[5] = v1.y; td[6] = v1.z; td[7] = v1.w;
    td[8] = v2.x; td[9] = v2.y; td[10] = v2.z; td[11] = v2.w;
    td[12] = v3.x; td[13] = v3.y; td[14] = v3.z; td[15] = v3.w;
  }
  __syncthreads();
  {
    int p = t >> 2, cs = t & 3;
    alignas(16) unsigned short tmp[16];
#pragma unroll
    for (int u = 0; u < 16; ++u) tmp[u] = f2bf(tile[(cs * 16 + u) * 68 + p]);
    unsigned short* dst = xT + (size_t)(bb * 3136 + pblk * 64 + p) * 256 +
                          cblk * 64 + cs * 16;
    ((uint4*)dst)[0] = *(const uint4*)(tmp);
    ((uint4*)dst)[1] = *(const uint4*)(tmp + 8);
  }
}

// ---------------------------------------------------------------------------
// Fused per-window kernel — round-6 numerics bit-exact; C4 restructured to
// stream dw-weight rows (kills the round-6 scratch spill: 139 -> ~60 live).
// LDS (74,112 B -> 2 blocks/CU), ALL regions dedicated (zero aliasing):
//   xw    [49][264] bf16 :      0 .. 25872
//   v_lds [65][56]  bf16 :  25872 .. 33152  (per-head; row 64 els0..7 = guard 0)
//   q_lds [64][72]  bf16 :  33152 .. 42368
//   k_lds [64][72]  bf16 :  42368 .. 51584
//   Sb    [64][72]  bf16 :  51584 .. 60800
//   spa   [64][52]  f32  :  60800 .. 74112  (raw PV, no attn_w folded)
// ---------------------------------------------------------------------------
__global__ __launch_bounds__(512, 4) void k2_win(
    const unsigned short* __restrict__ xT, const unsigned short* __restrict__ Wqk,
    const unsigned short* __restrict__ Wv, const float* __restrict__ bqk,
    const float* __restrict__ bv, const float* __restrict__ w3T,
    const float* __restrict__ w5T, const float* __restrict__ w7T,
    const float* __restrict__ aw, const float* __restrict__ c3w,
    const float* __restrict__ c5w, const float* __restrict__ c7w,
    unsigned short* __restrict__ xcT) {
  extern __shared__ char smem[];
  unsigned short* xw = (unsigned short*)smem;
  unsigned short* v_lds = (unsigned short*)(smem + 25872);
  unsigned short* q_lds = (unsigned short*)(smem + 33152);
  unsigned short* k_lds = (unsigned short*)(smem + 42368);
  unsigned short* Sb = (unsigned short*)(smem + 51584);
  float* spa = (float*)(smem + 60800);

  const int tid = threadIdx.x;
  const int l = tid & 63, w = tid >> 6, l15 = l & 15, lg = l >> 4;
  const int blk = blockIdx.x;
  const int bb = blk >> 6, i1 = (blk >> 3) & 7, i2 = blk & 7;

  // ---- A: gather window rows of xT into LDS [p][c]; zero v guard row
  for (int idx = tid; idx < 1568; idx += 512) {
    int r = idx >> 5, seg = idx & 31;
    int h1 = (r * 9363) >> 16, w1 = r - h1 * 7;
    int pix = bb * 3136 + (h1 * 8 + i1) * 56 + w1 * 8 + i2;
    *(uint4*)(xw + r * 264 + seg * 8) =
        *(const uint4*)(xT + (size_t)pix * 256 + seg * 8);
  }
  if (tid < 8) v_lds[64 * 56 + tid] = 0;  // PV row-overrun guard
  __syncthreads();

  // ---- per-head pipeline
  for (int h = 0; h < 4; ++h) {
    // C1: waves 0-3 -> q-tile w AND v-tile w; waves 4-7 -> k-tile (w-4).
    {
      const bool isq = (w < 4);
      const int wt = isq ? w : (w - 4);
      const int obase = isq ? (h * 64 + wt * 16) : (256 + h * 64 + wt * 16);
      f32x4 aq[4], av[4];
#pragma unroll
      for (int nt = 0; nt < 4; ++nt) {
        aq[nt] = (f32x4){0.f, 0.f, 0.f, 0.f};
        av[nt] = (f32x4){0.f, 0.f, 0.f, 0.f};
      }
#pragma unroll 2
      for (int ks = 0; ks < 8; ++ks) {
        bf16x8 b[4];
#pragma unroll
        for (int nt = 0; nt < 4; ++nt) {
          int j = nt * 16 + l15;
          if (j > 48) j = 48;
          b[nt] = *(const bf16x8*)(xw + j * 264 + ks * 32 + lg * 8);
        }
        bf16x8 a0 = *(const bf16x8*)(Wqk + (obase + l15) * 256 + ks * 32 + lg * 8);
#pragma unroll
        for (int nt = 0; nt < 4; ++nt) aq[nt] = MFMA16(a0, b[nt], aq[nt]);
        if (isq) {
          bf16x8 a1 =
              *(const bf16x8*)(Wv + (h * 64 + wt * 16 + l15) * 256 + ks * 32 + lg * 8);
#pragma unroll
          for (int nt = 0; nt < 4; ++nt) av[nt] = MFMA16(a1, b[nt], av[nt]);
        }
      }
      unsigned short* dst = isq ? q_lds : k_lds;
#pragma unroll
      for (int ri = 0; ri < 4; ++ri) {
        float bias = bqk[obase + lg * 4 + ri];
        int d = wt * 16 + lg * 4 + ri;
#pragma unroll
        for (int nt = 0; nt < 4; ++nt) {
          int p = nt * 16 + l15;
          dst[p * 72 + d] = f2bf(aq[nt][ri] + bias);
        }
      }
      if (isq) {
#pragma unroll
        for (int ri = 0; ri < 4; ++ri) {
          int cl = wt * 16 + lg * 4 + ri;
          float bvv = bv[h * 64 + cl];
#pragma unroll
          for (int nt = 0; nt < 4; ++nt) {
            int p = nt * 16 + l15;
            if (p < 56) v_lds[cl * 56 + p] = f2bf(av[nt][ri] + bvv);
          }
        }
      }
    }
    __syncthreads();

    // C2 (waves 0-3): S = q k^T, softmax in regs, write Sb (dedicated buffer)
    if (w < 4) {
      f32x4 s[4];
#pragma unroll
      for (int nt = 0; nt < 4; ++nt) s[nt] = (f32x4){0.f, 0.f, 0.f, 0.f};
#pragma unroll
      for (int ks = 0; ks < 2; ++ks) {
        bf16x8 a = *(const bf16x8*)(q_lds + (w * 16 + l15) * 72 + ks * 32 + lg * 8);
        bf16x8 b[4];
#pragma unroll
        for (int nt = 0; nt < 4; ++nt)
          b[nt] = *(const bf16x8*)(k_lds + (nt * 16 + l15) * 72 + ks * 32 + lg * 8);
#pragma unroll
        for (int nt = 0; nt < 4; ++nt) s[nt] = MFMA16(a, b[nt], s[nt]);
      }
#pragma unroll
      for (int ri = 0; ri < 4; ++ri) {
        float s0 = s[0][ri], s1 = s[1][ri], s2 = s[2][ri], s3 = s[3][ri];
        if (l15 != 0) s3 = -1e30f;  // mask j = 49..63
        float m = fmaxf(fmaxf(s0, s1), fmaxf(s2, s3));
        m = fmaxf(m, __shfl_xor(m, 1));
        m = fmaxf(m, __shfl_xor(m, 2));
        m = fmaxf(m, __shfl_xor(m, 4));
        m = fmaxf(m, __shfl_xor(m, 8));
        float e0 = __expf(s0 - m), e1 = __expf(s1 - m);
        float e2 = __expf(s2 - m), e3 = __expf(s3 - m);
        float sum = e0 + e1 + e2 + e3;
        sum += __shfl_xor(sum, 1);
        sum += __shfl_xor(sum, 2);
        sum += __shfl_xor(sum, 4);
        sum += __shfl_xor(sum, 8);
        float inv = 1.f / sum;
        int row = w * 16 + lg * 4 + ri;
        unsigned short* sb = Sb + row * 72 + l15;
        sb[0] = f2bf(e0 * inv);
        sb[16] = f2bf(e1 * inv);
        sb[32] = f2bf(e2 * inv);
        sb[48] = f2bf(e3 * inv);
      }
    }
    __syncthreads();

    // C3: PV (M=64 p, N=64 c', K=64) -> spa f32 (raw, no attn_w)
    {
      int pr = w & 3, nc = (w >> 2) * 2;
      f32x4 acc[2];
      acc[0] = (f32x4){0.f, 0.f, 0.f, 0.f};
      acc[1] = (f32x4){0.f, 0.f, 0.f, 0.f};
#pragma unroll
      for (int ks = 0; ks < 2; ++ks) {
        bf16x8 a = *(const bf16x8*)(Sb + (pr * 16 + l15) * 72 + ks * 32 + lg * 8);
#pragma unroll
        for (int t = 0; t < 2; ++t) {
          bf16x8 b = *(const bf16x8*)(v_lds + ((nc + t) * 16 + l15) * 56 +
                                      ks * 32 + lg * 8);
          acc[t] = MFMA16(a, b, acc[t]);
        }
      }
#pragma unroll
      for (int t = 0; t < 2; ++t) {
        int cl = (nc + t) * 16 + l15;
#pragma unroll
        for (int ri = 0; ri < 4; ++ri) {
          int p = pr * 16 + lg * 4 + ri;
          if (p < 49) spa[cl * 52 + p] = acc[t][ri];
        }
      }
    }
    __syncthreads();

    // C4: round-6 numerics bit-exact, register-light. Wave w = window row hr
    // (waves 0-6), lane = channel. Weight rows streamed per dy (<=15 live at a
    // time) instead of 83 preloaded; per-accumulator tap order is unchanged
    // ((dy,dx) lexicographic), so results are identical to round 6.
    if (w < 7) {
      int cl = l;
      int c = h * 64 + cl;
      int hr = w;  // wave-uniform window row
      float awc = aw[c], c3c = c3w[c], c5c = c5w[c], c7c = c7w[c];
      float s3a[7], s5a[7], s7a[7], vcen[7];
#pragma unroll
      for (int ww = 0; ww < 7; ++ww) {
        s3a[ww] = 0.f; s5a[ww] = 0.f; s7a[ww] = 0.f;
      }
#pragma unroll 1
      for (int dyi = 0; dyi < 7; ++dyi) {
        int ry = hr + dyi - 3;
        if ((unsigned)ry < 7u) {  // wave-uniform guard
          float vrow[7];
#pragma unroll
          for (int cc = 0; cc < 7; ++cc)
            vrow[cc] = bf2f(v_lds[cl * 56 + ry * 7 + cc]);
          if (dyi == 3) {
#pragma unroll
            for (int cc = 0; cc < 7; ++cc) vcen[cc] = vrow[cc];
          }
          // 7x7 taps
#pragma unroll
          for (int dx = 0; dx < 7; ++dx) {
            float wv = w7T[(dyi * 7 + dx) * 256 + c];
#pragma unroll
            for (int ww = 0; ww < 7; ++ww) {
              int cc = ww + dx - 3;
              if (cc >= 0 && cc < 7) s7a[ww] = fmaf(wv, vrow[cc], s7a[ww]);
            }
          }
          // 5x5 taps (dy in [-2,2])
          if (dyi >= 1 && dyi <= 5) {
#pragma unroll
            for (int dx = 0; dx < 5; ++dx) {
              float wv = w5T[((dyi - 1) * 5 + dx) * 256 + c];
#pragma unroll
              for (int ww = 0; ww < 7; ++ww) {
                int cc = ww + dx - 2;
                if (cc >= 0 && cc < 7) s5a[ww] = fmaf(wv, vrow[cc], s5a[ww]);
              }
            }
          }
          // 3x3 taps (dy in [-1,1])
          if (dyi >= 2 && dyi <= 4) {
#pragma unroll
            for (int dx = 0; dx < 3; ++dx) {
              float wv = w3T[((dyi - 2) * 3 + dx) * 256 + c];
#pragma unroll
              for (int ww = 0; ww < 7; ++ww) {
                int cc = ww + dx - 1;
                if (cc >= 0 && cc < 7) s3a[ww] = fmaf(wv, vrow[cc], s3a[ww]);
              }
            }
          }
        }
      }
      float sp[7];
#pragma unroll
      for (int ww = 0; ww < 7; ++ww) sp[ww] = spa[cl * 52 + hr * 7 + ww];
#pragma unroll
      for (int ww = 0; ww < 7; ++ww) {
        float val = fmaf(sp[ww], awc,
                    fmaf(s3a[ww], c3c,
                    fmaf(s5a[ww], c5c,
                    fmaf(s7a[ww], c7c, vcen[ww]))));
        int pixp = bb * 3136 + (hr * 8 + i1) * 56 + ww * 8 + i2;
        xcT[(size_t)pixp * 256 + c] = f2bf(val);
      }
    }
    __syncthreads();
  }
}

// ---------------------------------------------------------------------------
// Proj GEMM (M=256, N=pix, K=256) + shortcut residual, f32 out
// ---------------------------------------------------------------------------
__global__ __launch_bounds__(256) void k3_proj(const unsigned short* __restrict__ Wp,
                                               const unsigned short* __restrict__ xcT,
                                               const float* __restrict__ x,
                                               float* __restrict__ out) {
  const int tid = threadIdx.x, l = tid & 63, w = tid >> 6;
  const int l15 = l & 15, lg = l >> 4;
  const int blk = blockIdx.x;
  f32x4 acc[4][4];
#pragma unroll
  for (int mf = 0; mf < 4; ++mf)
#pragma unroll
    for (int nf = 0; nf < 4; ++nf) acc[mf][nf] = (f32x4){0.f, 0.f, 0.f, 0.f};
#pragma unroll 2
  for (int ks = 0; ks < 8; ++ks) {
    bf16x8 a[4], b[4];
#pragma unroll
    for (int mf = 0; mf < 4; ++mf)
      a[mf] = *(const bf16x8*)(Wp + (w * 64 + mf * 16 + l15) * 256 + ks * 32 + lg * 8);
#pragma unroll
    for (int nf = 0; nf < 4; ++nf)
      b[nf] = *(const bf16x8*)(xcT + (size_t)(blk * 64 + nf * 16 + l15) * 256 +
                               ks * 32 + lg * 8);
#pragma unroll
    for (int mf = 0; mf < 4; ++mf)
#pragma unroll
      for (int nf = 0; nf < 4; ++nf) acc[mf][nf] = MFMA16(a[mf], b[nf], acc[mf][nf]);
  }
  int bb = (blk * 64) / 3136;
  int loc0 = blk * 64 - bb * 3136;
#pragma unroll
  for (int mf = 0; mf < 4; ++mf)
#pragma unroll
    for (int nf = 0; nf < 4; ++nf)
#pragma unroll
      for (int ri = 0; ri < 4; ++ri) {
        int o = w * 64 + mf * 16 + lg * 4 + ri;
        int ploc = loc0 + nf * 16 + l15;
        size_t addr = (size_t)bb * 802816 + (size_t)o * 3136 + ploc;
        out[addr] = x[addr] + acc[mf][nf][ri];
      }
}

// ---------------------------------------------------------------------------
extern "C" void kernel_launch(void* const* d_in, const int* in_sizes, int n_in,
                              void* d_out, int out_size, void* d_ws, size_t ws_size,
                              hipStream_t stream) {
  const float* x = (const float*)d_in[0];
  const float* bn_g = (const float*)d_in[1];
  const float* bn_b = (const float*)d_in[2];
  const float* bn_m = (const float*)d_in[3];
  const float* bn_v = (const float*)d_in[4];
  const float* w_qk = (const float*)d_in[5];
  const float* w_v = (const float*)d_in[6];
  const float* w3 = (const float*)d_in[7];
  const float* w5 = (const float*)d_in[8];
  const float* w7 = (const float*)d_in[9];
  const float* aw = (const float*)d_in[10];
  const float* c3w = (const float*)d_in[11];
  const float* c5w = (const float*)d_in[12];
  const float* c7w = (const float*)d_in[13];
  const float* w_pr = (const float*)d_in[14];
  float* out = (float*)d_out;
  char* ws = (char*)d_ws;

  unsigned short* Wqk = (unsigned short*)ws;               // 512x256 bf16
  unsigned short* Wv = (unsigned short*)(ws + 262144);     // 256x256 bf16
  unsigned short* Wp = (unsigned short*)(ws + 393216);     // 256x256 bf16
  float* bqk = (float*)(ws + 524288);                      // 512 f32
  float* bv = (float*)(ws + 526336);                       // 256 f32
  float* w3T = (float*)(ws + 527360);                      // 9x256
  float* w5T = (float*)(ws + 536576);                      // 25x256
  float* w7T = (float*)(ws + 562176);                      // 49x256
  unsigned short* xT = (unsigned short*)(ws + 1048576);    // 100352x256 bf16
  unsigned short* xcT = (unsigned short*)(ws + 52428800);  // 100352x256 bf16

  wprep<<<5, 256, 0, stream>>>(bn_g, bn_b, bn_m, bn_v, w_qk, w_v, w_pr, w3, w5, w7,
                               Wqk, Wv, Wp, bqk, bv, w3T, w5T, w7T);
  xpose<<<6272, 256, 0, stream>>>(x, xT);
  hipFuncSetAttribute(reinterpret_cast<const void*>(k2_win),
                      hipFuncAttributeMaxDynamicSharedMemorySize, 74112);
  k2_win<<<2048, 512, 74112, stream>>>(xT, Wqk, Wv, bqk, bv, w3T, w5T, w7T, aw, c3w,
                                       c5w, c7w, xcT);
  k3_proj<<<1568, 256, 0, stream>>>(Wp, xcT, x, out);
}

// Round 8
// 346.185 us; speedup vs baseline: 3.1060x; 1.0175x over previous
//
#include <hip/hip_runtime.h>
#include <cstddef>
#include <cstdint>

typedef short bf16x8 __attribute__((ext_vector_type(8)));
typedef float f32x4 __attribute__((ext_vector_type(4)));

#define MFMA16(a, b, c) __builtin_amdgcn_mfma_f32_16x16x32_bf16((a), (b), (c), 0, 0, 0)

__device__ __forceinline__ unsigned short f2bf(float f) {
  unsigned u = __float_as_uint(f);
  u = (u + 0x7FFFu + ((u >> 16) & 1u)) >> 16;
  return (unsigned short)u;
}
__device__ __forceinline__ float bf2f(unsigned short h) {
  return __uint_as_float(((unsigned)h) << 16);
}

// ---------------------------------------------------------------------------
// Weight prep: fold BN into Wqk/Wv (bf16) + f32 bias; cast Wproj; transpose dw
// weights to [k][c].
// ---------------------------------------------------------------------------
__global__ void wprep(const float* __restrict__ bn_g, const float* __restrict__ bn_b,
                      const float* __restrict__ bn_m, const float* __restrict__ bn_v,
                      const float* __restrict__ w_qk, const float* __restrict__ w_v,
                      const float* __restrict__ w_proj,
                      const float* __restrict__ w3, const float* __restrict__ w5,
                      const float* __restrict__ w7,
                      unsigned short* __restrict__ Wqk, unsigned short* __restrict__ Wv,
                      unsigned short* __restrict__ Wp,
                      float* __restrict__ bqk, float* __restrict__ bv,
                      float* __restrict__ w3T, float* __restrict__ w5T,
                      float* __restrict__ w7T) {
  int blk = blockIdx.x, t = threadIdx.x;
  if (blk == 4) {
    for (int idx = t; idx < 21248; idx += 256) {
      if (idx < 2304) {
        int k2 = idx >> 8, c = idx & 255;
        w3T[idx] = w3[c * 9 + k2];
      } else if (idx < 8704) {
        int i = idx - 2304;
        int k2 = i >> 8, c = i & 255;
        w5T[i] = w5[c * 25 + k2];
      } else {
        int i = idx - 8704;
        int k2 = i >> 8, c = i & 255;
        w7T[i] = w7[c * 49 + k2];
      }
    }
    return;
  }
  int o = blk * 256 + t;  // 0..1023
  if (o < 512) {
    float scale = (o < 256) ? 0.125f : 1.0f;  // q rows get 1/sqrt(64)
    float bias = 0.f;
    for (int c = 0; c < 256; ++c) {
      float g = bn_g[c] / sqrtf(bn_v[c] + 1e-5f);
      float be = bn_b[c] - bn_m[c] * g;
      float wv = w_qk[o * 256 + c];
      bias += wv * be;
      Wqk[o * 256 + c] = f2bf(wv * g * scale);
    }
    bqk[o] = bias * scale;
  } else if (o < 768) {
    int oo = o - 512;
    float bias = 0.f;
    for (int c = 0; c < 256; ++c) {
      float g = bn_g[c] / sqrtf(bn_v[c] + 1e-5f);
      float be = bn_b[c] - bn_m[c] * g;
      float wv = w_v[oo * 256 + c];
      bias += wv * be;
      Wv[oo * 256 + c] = f2bf(wv * g);
    }
    bv[oo] = bias;
  } else {
    int oo = o - 768;
    for (int c = 0; c < 256; ++c) Wp[oo * 256 + c] = f2bf(w_proj[oo * 256 + c]);
  }
}

// ---------------------------------------------------------------------------
// Transpose+cast: x f32 [32][256][3136] -> xT bf16 [pix=32*3136][256]
// ---------------------------------------------------------------------------
__global__ __launch_bounds__(256) void xpose(const float* __restrict__ x,
                                             unsigned short* __restrict__ xT) {
  __shared__ float tile[64 * 68];
  int blk = blockIdx.x;
  int bb = blk / 196;
  int rem = blk - bb * 196;
  int cblk = rem / 49;
  int pblk = rem - cblk * 49;
  int t = threadIdx.x;
  {
    int r = t >> 2, seg = t & 3;
    const float* src = x + (size_t)bb * 802816 + (size_t)(cblk * 64 + r) * 3136 +
                       pblk * 64 + seg * 16;
    float4 v0 = ((const float4*)src)[0];
    float4 v1 = ((const float4*)src)[1];
    float4 v2 = ((const float4*)src)[2];
    float4 v3 = ((const float4*)src)[3];
    float* td = tile + r * 68 + seg * 16;
    td[0] = v0.x; td[1] = v0.y; td[2] = v0.z; td[3] = v0.w;
    td[4] = v1.x; td[5] = v1.y; td[6] = v1.z; td[7] = v1.w;
    td[8] = v2.x; td[9] = v2.y; td[10] = v2.z; td[11] = v2.w;
    td[12] = v3.x; td[13] = v3.y; td[14] = v3.z; td[15] = v3.w;
  }
  __syncthreads();
  {
    int p = t >> 2, cs = t & 3;
    alignas(16) unsigned short tmp[16];
#pragma unroll
    for (int u = 0; u < 16; ++u) tmp[u] = f2bf(tile[(cs * 16 + u) * 68 + p]);
    unsigned short* dst = xT + (size_t)(bb * 3136 + pblk * 64 + p) * 256 +
                          cblk * 64 + cs * 16;
    ((uint4*)dst)[0] = *(const uint4*)(tmp);
    ((uint4*)dst)[1] = *(const uint4*)(tmp + 8);
  }
}

// ---------------------------------------------------------------------------
// Fused per-window kernel — round-7 numerics BIT-EXACT, software-pipelined:
//   Phase A(h): w0-3 C2(h) softmax  ||  w4-7 v(h+1) GEMM -> vbuf[nxt]
//   Phase B(h): w0-3 C3(h) PV      ||  w4-7 q(h+1)+k(h+1) GEMM
//   Phase C(h): w0-6 C4(h) conv + global write
// LDS (81,392 B -> 2 blocks/CU; 2x81,392 = 162,784 <= 163,840):
//   xw    [49][264] bf16 :      0 .. 25872
//   vbuf0 [65][56]  bf16 :  25872 .. 33152  (row 64 els0..7 = guard 0)
//   vbuf1 [65][56]  bf16 :  33152 .. 40432  (row 64 els0..7 = guard 0)
//   q_lds [64][72]  bf16 :  40432 .. 49648
//   k_lds [64][72]  bf16 :  49648 .. 58864
//   Sb    [64][72]  bf16 :  58864 .. 68080
//   spa   [64][52]  f32  :  68080 .. 81392
// Hazards: q/k written in B(h) for h+1, read in A(h+1) C2 (barrier-separated).
// vbuf[nxt] written in A(h); vbuf[cur] read in B(h)/C(h) (different buffer).
// ---------------------------------------------------------------------------
__global__ __launch_bounds__(512, 4) void k2_win(
    const unsigned short* __restrict__ xT, const unsigned short* __restrict__ Wqk,
    const unsigned short* __restrict__ Wv, const float* __restrict__ bqk,
    const float* __restrict__ bv, const float* __restrict__ w3T,
    const float* __restrict__ w5T, const float* __restrict__ w7T,
    const float* __restrict__ aw, const float* __restrict__ c3w,
    const float* __restrict__ c5w, const float* __restrict__ c7w,
    unsigned short* __restrict__ xcT) {
  extern __shared__ char smem[];
  unsigned short* xw = (unsigned short*)smem;
  unsigned short* vbuf0 = (unsigned short*)(smem + 25872);
  unsigned short* vbuf1 = (unsigned short*)(smem + 33152);
  unsigned short* q_lds = (unsigned short*)(smem + 40432);
  unsigned short* k_lds = (unsigned short*)(smem + 49648);
  unsigned short* Sb = (unsigned short*)(smem + 58864);
  float* spa = (float*)(smem + 68080);

  const int tid = threadIdx.x;
  const int l = tid & 63, w = tid >> 6, l15 = l & 15, lg = l >> 4;
  const int blk = blockIdx.x;
  const int bb = blk >> 6, i1 = (blk >> 3) & 7, i2 = blk & 7;

  // ---- A: gather window rows of xT into LDS [p][c]; zero both v guard rows
  for (int idx = tid; idx < 1568; idx += 512) {
    int r = idx >> 5, seg = idx & 31;
    int h1 = (r * 9363) >> 16, w1 = r - h1 * 7;
    int pix = bb * 3136 + (h1 * 8 + i1) * 56 + w1 * 8 + i2;
    *(uint4*)(xw + r * 264 + seg * 8) =
        *(const uint4*)(xT + (size_t)pix * 256 + seg * 8);
  }
  if (tid < 8) vbuf0[64 * 56 + tid] = 0;
  else if (tid < 16) vbuf1[64 * 56 + (tid - 8)] = 0;
  __syncthreads();

  // ---- Prologue: C1(0) — exactly round-7 C1 (h=0), v -> vbuf0
  {
    const bool isq = (w < 4);
    const int wt = isq ? w : (w - 4);
    const int obase = isq ? (wt * 16) : (256 + wt * 16);
    f32x4 aq[4], av[4];
#pragma unroll
    for (int nt = 0; nt < 4; ++nt) {
      aq[nt] = (f32x4){0.f, 0.f, 0.f, 0.f};
      av[nt] = (f32x4){0.f, 0.f, 0.f, 0.f};
    }
#pragma unroll 2
    for (int ks = 0; ks < 8; ++ks) {
      bf16x8 b[4];
#pragma unroll
      for (int nt = 0; nt < 4; ++nt) {
        int j = nt * 16 + l15;
        if (j > 48) j = 48;
        b[nt] = *(const bf16x8*)(xw + j * 264 + ks * 32 + lg * 8);
      }
      bf16x8 a0 = *(const bf16x8*)(Wqk + (obase + l15) * 256 + ks * 32 + lg * 8);
#pragma unroll
      for (int nt = 0; nt < 4; ++nt) aq[nt] = MFMA16(a0, b[nt], aq[nt]);
      if (isq) {
        bf16x8 a1 = *(const bf16x8*)(Wv + (wt * 16 + l15) * 256 + ks * 32 + lg * 8);
#pragma unroll
        for (int nt = 0; nt < 4; ++nt) av[nt] = MFMA16(a1, b[nt], av[nt]);
      }
    }
    unsigned short* dst = isq ? q_lds : k_lds;
#pragma unroll
    for (int ri = 0; ri < 4; ++ri) {
      float bias = bqk[obase + lg * 4 + ri];
      int d = wt * 16 + lg * 4 + ri;
#pragma unroll
      for (int nt = 0; nt < 4; ++nt) {
        int p = nt * 16 + l15;
        dst[p * 72 + d] = f2bf(aq[nt][ri] + bias);
      }
    }
    if (isq) {
#pragma unroll
      for (int ri = 0; ri < 4; ++ri) {
        int cl = wt * 16 + lg * 4 + ri;
        float bvv = bv[cl];
#pragma unroll
        for (int nt = 0; nt < 4; ++nt) {
          int p = nt * 16 + l15;
          if (p < 56) vbuf0[cl * 56 + p] = f2bf(av[nt][ri] + bvv);
        }
      }
    }
  }
  __syncthreads();

  // ---- per-head pipelined loop
  for (int h = 0; h < 4; ++h) {
    unsigned short* vcur = (h & 1) ? vbuf1 : vbuf0;
    unsigned short* vnxt = (h & 1) ? vbuf0 : vbuf1;

    // ===== Phase A: C2(h) on waves 0-3  ||  v(h+1) on waves 4-7
    if (w < 4) {
      f32x4 s[4];
#pragma unroll
      for (int nt = 0; nt < 4; ++nt) s[nt] = (f32x4){0.f, 0.f, 0.f, 0.f};
#pragma unroll
      for (int ks = 0; ks < 2; ++ks) {
        bf16x8 a = *(const bf16x8*)(q_lds + (w * 16 + l15) * 72 + ks * 32 + lg * 8);
        bf16x8 b[4];
#pragma unroll
        for (int nt = 0; nt < 4; ++nt)
          b[nt] = *(const bf16x8*)(k_lds + (nt * 16 + l15) * 72 + ks * 32 + lg * 8);
#pragma unroll
        for (int nt = 0; nt < 4; ++nt) s[nt] = MFMA16(a, b[nt], s[nt]);
      }
#pragma unroll
      for (int ri = 0; ri < 4; ++ri) {
        float s0 = s[0][ri], s1 = s[1][ri], s2 = s[2][ri], s3 = s[3][ri];
        if (l15 != 0) s3 = -1e30f;  // mask j = 49..63
        float m = fmaxf(fmaxf(s0, s1), fmaxf(s2, s3));
        m = fmaxf(m, __shfl_xor(m, 1));
        m = fmaxf(m, __shfl_xor(m, 2));
        m = fmaxf(m, __shfl_xor(m, 4));
        m = fmaxf(m, __shfl_xor(m, 8));
        float e0 = __expf(s0 - m), e1 = __expf(s1 - m);
        float e2 = __expf(s2 - m), e3 = __expf(s3 - m);
        float sum = e0 + e1 + e2 + e3;
        sum += __shfl_xor(sum, 1);
        sum += __shfl_xor(sum, 2);
        sum += __shfl_xor(sum, 4);
        sum += __shfl_xor(sum, 8);
        float inv = 1.f / sum;
        int row = w * 16 + lg * 4 + ri;
        unsigned short* sb = Sb + row * 72 + l15;
        sb[0] = f2bf(e0 * inv);
        sb[16] = f2bf(e1 * inv);
        sb[32] = f2bf(e2 * inv);
        sb[48] = f2bf(e3 * inv);
      }
    } else if (h < 3) {
      // v(h+1), tile wt = w-4 -> vnxt  (same per-tile MFMA sequence as C1's v)
      int wt = w - 4;
      f32x4 av[4];
#pragma unroll
      for (int nt = 0; nt < 4; ++nt) av[nt] = (f32x4){0.f, 0.f, 0.f, 0.f};
#pragma unroll 2
      for (int ks = 0; ks < 8; ++ks) {
        bf16x8 b[4];
#pragma unroll
        for (int nt = 0; nt < 4; ++nt) {
          int j = nt * 16 + l15;
          if (j > 48) j = 48;
          b[nt] = *(const bf16x8*)(xw + j * 264 + ks * 32 + lg * 8);
        }
        bf16x8 a1 = *(const bf16x8*)(Wv + ((h + 1) * 64 + wt * 16 + l15) * 256 +
                                     ks * 32 + lg * 8);
#pragma unroll
        for (int nt = 0; nt < 4; ++nt) av[nt] = MFMA16(a1, b[nt], av[nt]);
      }
#pragma unroll
      for (int ri = 0; ri < 4; ++ri) {
        int cl = wt * 16 + lg * 4 + ri;
        float bvv = bv[(h + 1) * 64 + cl];
#pragma unroll
        for (int nt = 0; nt < 4; ++nt) {
          int p = nt * 16 + l15;
          if (p < 56) vnxt[cl * 56 + p] = f2bf(av[nt][ri] + bvv);
        }
      }
    }
    __syncthreads();

    // ===== Phase B: C3(h) on waves 0-3 (4 tiles each)  ||  q/k(h+1) on 4-7
    if (w < 4) {
      int pr = w;
      f32x4 acc[4];
#pragma unroll
      for (int t = 0; t < 4; ++t) acc[t] = (f32x4){0.f, 0.f, 0.f, 0.f};
#pragma unroll
      for (int ks = 0; ks < 2; ++ks) {
        bf16x8 a = *(const bf16x8*)(Sb + (pr * 16 + l15) * 72 + ks * 32 + lg * 8);
#pragma unroll
        for (int t = 0; t < 4; ++t) {
          bf16x8 b = *(const bf16x8*)(vcur + (t * 16 + l15) * 56 + ks * 32 + lg * 8);
          acc[t] = MFMA16(a, b, acc[t]);
        }
      }
#pragma unroll
      for (int t = 0; t < 4; ++t) {
        int cl = t * 16 + l15;
#pragma unroll
        for (int ri = 0; ri < 4; ++ri) {
          int p = pr * 16 + lg * 4 + ri;
          if (p < 49) spa[cl * 52 + p] = acc[t][ri];
        }
      }
    } else if (h < 3) {
      // q(h+1) and k(h+1), tile wt = w-4 each (2 A-frags per b-load)
      int wt = w - 4;
      int obq = (h + 1) * 64 + wt * 16;
      int obk = 256 + (h + 1) * 64 + wt * 16;
      f32x4 aq[4], ak[4];
#pragma unroll
      for (int nt = 0; nt < 4; ++nt) {
        aq[nt] = (f32x4){0.f, 0.f, 0.f, 0.f};
        ak[nt] = (f32x4){0.f, 0.f, 0.f, 0.f};
      }
#pragma unroll 2
      for (int ks = 0; ks < 8; ++ks) {
        bf16x8 b[4];
#pragma unroll
        for (int nt = 0; nt < 4; ++nt) {
          int j = nt * 16 + l15;
          if (j > 48) j = 48;
          b[nt] = *(const bf16x8*)(xw + j * 264 + ks * 32 + lg * 8);
        }
        bf16x8 a0 = *(const bf16x8*)(Wqk + (obq + l15) * 256 + ks * 32 + lg * 8);
        bf16x8 a1 = *(const bf16x8*)(Wqk + (obk + l15) * 256 + ks * 32 + lg * 8);
#pragma unroll
        for (int nt = 0; nt < 4; ++nt) {
          aq[nt] = MFMA16(a0, b[nt], aq[nt]);
          ak[nt] = MFMA16(a1, b[nt], ak[nt]);
        }
      }
#pragma unroll
      for (int ri = 0; ri < 4; ++ri) {
        float biasq = bqk[obq + lg * 4 + ri];
        float biask = bqk[obk + lg * 4 + ri];
        int d = wt * 16 + lg * 4 + ri;
#pragma unroll
        for (int nt = 0; nt < 4; ++nt) {
          int p = nt * 16 + l15;
          q_lds[p * 72 + d] = f2bf(aq[nt][ri] + biasq);
          k_lds[p * 72 + d] = f2bf(ak[nt][ri] + biask);
        }
      }
    }
    __syncthreads();

    // ===== Phase C: C4(h) conv on waves 0-6 (round-7 code, vcur)
    if (w < 7) {
      int cl = l;
      int c = h * 64 + cl;
      int hr = w;  // wave-uniform window row
      float awc = aw[c], c3c = c3w[c], c5c = c5w[c], c7c = c7w[c];
      float s3a[7], s5a[7], s7a[7], vcen[7];
#pragma unroll
      for (int ww = 0; ww < 7; ++ww) {
        s3a[ww] = 0.f; s5a[ww] = 0.f; s7a[ww] = 0.f;
      }
#pragma unroll 1
      for (int dyi = 0; dyi < 7; ++dyi) {
        int ry = hr + dyi - 3;
        if ((unsigned)ry < 7u) {  // wave-uniform guard
          float vrow[7];
#pragma unroll
          for (int cc = 0; cc < 7; ++cc)
            vrow[cc] = bf2f(vcur[cl * 56 + ry * 7 + cc]);
          if (dyi == 3) {
#pragma unroll
            for (int cc = 0; cc < 7; ++cc) vcen[cc] = vrow[cc];
          }
#pragma unroll
          for (int dx = 0; dx < 7; ++dx) {
            float wv = w7T[(dyi * 7 + dx) * 256 + c];
#pragma unroll
            for (int ww = 0; ww < 7; ++ww) {
              int cc = ww + dx - 3;
              if (cc >= 0 && cc < 7) s7a[ww] = fmaf(wv, vrow[cc], s7a[ww]);
            }
          }
          if (dyi >= 1 && dyi <= 5) {
#pragma unroll
            for (int dx = 0; dx < 5; ++dx) {
              float wv = w5T[((dyi - 1) * 5 + dx) * 256 + c];
#pragma unroll
              for (int ww = 0; ww < 7; ++ww) {
                int cc = ww + dx - 2;
                if (cc >= 0 && cc < 7) s5a[ww] = fmaf(wv, vrow[cc], s5a[ww]);
              }
            }
          }
          if (dyi >= 2 && dyi <= 4) {
#pragma unroll
            for (int dx = 0; dx < 3; ++dx) {
              float wv = w3T[((dyi - 2) * 3 + dx) * 256 + c];
#pragma unroll
              for (int ww = 0; ww < 7; ++ww) {
                int cc = ww + dx - 1;
                if (cc >= 0 && cc < 7) s3a[ww] = fmaf(wv, vrow[cc], s3a[ww]);
              }
            }
          }
        }
      }
      float sp[7];
#pragma unroll
      for (int ww = 0; ww < 7; ++ww) sp[ww] = spa[cl * 52 + hr * 7 + ww];
#pragma unroll
      for (int ww = 0; ww < 7; ++ww) {
        float val = fmaf(sp[ww], awc,
                    fmaf(s3a[ww], c3c,
                    fmaf(s5a[ww], c5c,
                    fmaf(s7a[ww], c7c, vcen[ww]))));
        int pixp = bb * 3136 + (hr * 8 + i1) * 56 + ww * 8 + i2;
        xcT[(size_t)pixp * 256 + c] = f2bf(val);
      }
    }
    __syncthreads();
  }
}

// ---------------------------------------------------------------------------
// Proj GEMM (M=256, N=pix, K=256) + shortcut residual, f32 out
// ---------------------------------------------------------------------------
__global__ __launch_bounds__(256) void k3_proj(const unsigned short* __restrict__ Wp,
                                               const unsigned short* __restrict__ xcT,
                                               const float* __restrict__ x,
                                               float* __restrict__ out) {
  const int tid = threadIdx.x, l = tid & 63, w = tid >> 6;
  const int l15 = l & 15, lg = l >> 4;
  const int blk = blockIdx.x;
  f32x4 acc[4][4];
#pragma unroll
  for (int mf = 0; mf < 4; ++mf)
#pragma unroll
    for (int nf = 0; nf < 4; ++nf) acc[mf][nf] = (f32x4){0.f, 0.f, 0.f, 0.f};
#pragma unroll 2
  for (int ks = 0; ks < 8; ++ks) {
    bf16x8 a[4], b[4];
#pragma unroll
    for (int mf = 0; mf < 4; ++mf)
      a[mf] = *(const bf16x8*)(Wp + (w * 64 + mf * 16 + l15) * 256 + ks * 32 + lg * 8);
#pragma unroll
    for (int nf = 0; nf < 4; ++nf)
      b[nf] = *(const bf16x8*)(xcT + (size_t)(blk * 64 + nf * 16 + l15) * 256 +
                               ks * 32 + lg * 8);
#pragma unroll
    for (int mf = 0; mf < 4; ++mf)
#pragma unroll
      for (int nf = 0; nf < 4; ++nf) acc[mf][nf] = MFMA16(a[mf], b[nf], acc[mf][nf]);
  }
  int bb = (blk * 64) / 3136;
  int loc0 = blk * 64 - bb * 3136;
#pragma unroll
  for (int mf = 0; mf < 4; ++mf)
#pragma unroll
    for (int nf = 0; nf < 4; ++nf)
#pragma unroll
      for (int ri = 0; ri < 4; ++ri) {
        int o = w * 64 + mf * 16 + lg * 4 + ri;
        int ploc = loc0 + nf * 16 + l15;
        size_t addr = (size_t)bb * 802816 + (size_t)o * 3136 + ploc;
        out[addr] = x[addr] + acc[mf][nf][ri];
      }
}

// ---------------------------------------------------------------------------
extern "C" void kernel_launch(void* const* d_in, const int* in_sizes, int n_in,
                              void* d_out, int out_size, void* d_ws, size_t ws_size,
                              hipStream_t stream) {
  const float* x = (const float*)d_in[0];
  const float* bn_g = (const float*)d_in[1];
  const float* bn_b = (const float*)d_in[2];
  const float* bn_m = (const float*)d_in[3];
  const float* bn_v = (const float*)d_in[4];
  const float* w_qk = (const float*)d_in[5];
  const float* w_v = (const float*)d_in[6];
  const float* w3 = (const float*)d_in[7];
  const float* w5 = (const float*)d_in[8];
  const float* w7 = (const float*)d_in[9];
  const float* aw = (const float*)d_in[10];
  const float* c3w = (const float*)d_in[11];
  const float* c5w = (const float*)d_in[12];
  const float* c7w = (const float*)d_in[13];
  const float* w_pr = (const float*)d_in[14];
  float* out = (float*)d_out;
  char* ws = (char*)d_ws;

  unsigned short* Wqk = (unsigned short*)ws;               // 512x256 bf16
  unsigned short* Wv = (unsigned short*)(ws + 262144);     // 256x256 bf16
  unsigned short* Wp = (unsigned short*)(ws + 393216);     // 256x256 bf16
  float* bqk = (float*)(ws + 524288);                      // 512 f32
  float* bv = (float*)(ws + 526336);                       // 256 f32
  float* w3T = (float*)(ws + 527360);                      // 9x256
  float* w5T = (float*)(ws + 536576);                      // 25x256
  float* w7T = (float*)(ws + 562176);                      // 49x256
  unsigned short* xT = (unsigned short*)(ws + 1048576);    // 100352x256 bf16
  unsigned short* xcT = (unsigned short*)(ws + 52428800);  // 100352x256 bf16

  wprep<<<5, 256, 0, stream>>>(bn_g, bn_b, bn_m, bn_v, w_qk, w_v, w_pr, w3, w5, w7,
                               Wqk, Wv, Wp, bqk, bv, w3T, w5T, w7T);
  xpose<<<6272, 256, 0, stream>>>(x, xT);
  hipFuncSetAttribute(reinterpret_cast<const void*>(k2_win),
                      hipFuncAttributeMaxDynamicSharedMemorySize, 81392);
  k2_win<<<2048, 512, 81392, stream>>>(xT, Wqk, Wv, bqk, bv, w3T, w5T, w7T, aw, c3w,
                                       c5w, c7w, xcT);
  k3_proj<<<1568, 256, 0, stream>>>(Wp, xcT, x, out);
}